// Round 1
// baseline (454.612 us; speedup 1.0000x reference)
//
#include <hip/hip_runtime.h>
#include <math.h>

#define NN 16384      // B*N total nodes
#define NPB 4096      // nodes per batch

__device__ __forceinline__ float gelu_f(float v){
  return 0.5f*v*(1.0f+erff(v*0.70710678118654752440f));
}

// ---------------- kNN: per-wave node, register top-16 + shuffle merge ----------------
__global__ __launch_bounds__(256) void knn_k(const float* __restrict__ x, int* __restrict__ nbr){
  __shared__ unsigned long long mergebuf[4][1024];
  const int w = threadIdx.x >> 6, lane = threadIdx.x & 63;
  const int n = blockIdx.x*4 + w;
  const int base = n & ~(NPB-1);
  const float* xn = x + n*6;
  const float x0=xn[0],x1=xn[1],x2=xn[2],x3=xn[3],x4=xn[4],x5=xn[5];
  const float sqn = x0*x0+x1*x1+x2*x2+x3*x3+x4*x4+x5*x5;
  unsigned long long lst[16];
#pragma unroll
  for (int i=0;i<16;i++) lst[i] = ~0ull;
  for (int t=0;t<64;t++){
    const int j = base + t*64 + lane;
    const float* xj = x + j*6;
    const float y0=xj[0],y1=xj[1],y2=xj[2],y3=xj[3],y4=xj[4],y5=xj[5];
    const float sqj = y0*y0+y1*y1+y2*y2+y3*y3+y4*y4+y5*y5;
    const float dot = x0*y0+x1*y1+x2*y2+x3*y3+x4*y4+x5*y5;
    const float d2 = sqn + sqj - 2.0f*dot;
    unsigned u = __float_as_uint(d2);
    u = (u & 0x80000000u) ? ~u : (u | 0x80000000u);   // monotone float->uint map
    unsigned long long key = ((unsigned long long)u << 32) | (unsigned)j;
    if (j == n) key = ~0ull;                           // exclude self (inf diagonal)
    if (key < lst[15]){
      lst[15] = key;
#pragma unroll
      for (int kk=15;kk>0;--kk){
        unsigned long long a=lst[kk-1], b=lst[kk];
        const bool sw = b < a;
        lst[kk-1] = sw ? b : a;
        lst[kk]   = sw ? a : b;
      }
    }
  }
#pragma unroll
  for (int i=0;i<16;i++) mergebuf[w][lane*16+i] = lst[i];
  __syncthreads();
  int hp = 0;
  unsigned long long cur = lst[0];
  for (int p=0;p<16;p++){
    unsigned long long m = cur;
#pragma unroll
    for (int off=1; off<64; off<<=1){
      unsigned long long o = __shfl_xor(m, off);
      m = (o < m) ? o : m;
    }
    if (lane == 0) nbr[n*16+p] = (int)(m & 0xffffffffull);
    if (cur == m){
      hp++;
      cur = (hp < 16) ? mergebuf[w][lane*16+hp] : ~0ull;
    }
  }
}

// ---------------- layer-1 GEMM: x[NN,6] @ W1[6,256] ----------------
__global__ __launch_bounds__(256) void gemm_in6(const float* __restrict__ x, const float* __restrict__ W,
                                                float* __restrict__ h){
  const int t = blockIdx.x*256 + threadIdx.x;  // over NN*64
  const int n = t >> 6, cg = t & 63;
  const float* xr = x + n*6;
  float xv[6];
#pragma unroll
  for (int d=0; d<6; d++) xv[d] = xr[d];
  float4 acc = make_float4(0.f,0.f,0.f,0.f);
#pragma unroll
  for (int d=0; d<6; d++){
    const float4 wv = *(const float4*)(W + d*256 + cg*4);
    acc.x += xv[d]*wv.x; acc.y += xv[d]*wv.y; acc.z += xv[d]*wv.z; acc.w += xv[d]*wv.w;
  }
  *(float4*)(h + n*256 + cg*4) = acc;
}

// ---------------- residual: y[NN,128] += x@res_W + res_b ----------------
__global__ __launch_bounds__(256) void res_k(const float* __restrict__ x, const float* __restrict__ W,
                                             const float* __restrict__ b, float* __restrict__ y){
  const int t = blockIdx.x*256 + threadIdx.x;  // over NN*128
  const int n = t >> 7, c = t & 127;
  const float* xr = x + n*6;
  float acc = b[c];
#pragma unroll
  for (int d=0; d<6; d++) acc += xr[d]*W[d*128 + c];
  y[t] += acc;
}

// ---------------- attention logits: als/ald [NN,HEADS] ----------------
template<int HEADS, int C>
__global__ __launch_bounds__(256) void al_k(const float* __restrict__ h, const float* __restrict__ asrc,
                                            const float* __restrict__ adst, float* __restrict__ als,
                                            float* __restrict__ ald){
  const int t = blockIdx.x*256 + threadIdx.x;  // over NN*HEADS
  const int n = t / HEADS, hd = t % HEADS;
  const float* hp = h + (n*HEADS + hd)*C;
  const float* ap = asrc + hd*C;
  const float* dp = adst + hd*C;
  float s=0.f, d=0.f;
#pragma unroll 4
  for (int c=0;c<C;c+=4){
    const float4 v = *(const float4*)(hp+c);
    const float4 a = *(const float4*)(ap+c);
    const float4 b = *(const float4*)(dp+c);
    s += v.x*a.x + v.y*a.y + v.z*a.z + v.w*a.w;
    d += v.x*b.x + v.y*b.y + v.z*b.z + v.w*b.w;
  }
  als[t] = s; ald[t] = d;
}

// ---------------- GAT aggregation: one wave per node, 17-way softmax gather ----------------
template<int HEADS, int C>
__global__ __launch_bounds__(256) void agg_k(const float* __restrict__ h, const float* __restrict__ als,
                                             const float* __restrict__ ald, const int* __restrict__ nbr,
                                             const float* __restrict__ bias, float* __restrict__ out){
  constexpr int CT = HEADS*C;
  constexpr int F  = CT/64;
  const int w = threadIdx.x >> 6, lane = threadIdx.x & 63;
  const int n = blockIdx.x*4 + w;
  const int head = (lane*F)/C;
  const int col  = lane*F;
  const int nb = nbr[n*16 + (lane & 15)];
  const float aldn = ald[n*HEADS + head];
  float e[17];
#pragma unroll
  for (int j=0;j<17;j++){
    const int sj = (j<16) ? __shfl(nb, j) : n;
    const float v = als[sj*HEADS + head] + aldn;
    e[j] = v > 0.f ? v : 0.2f*v;
  }
  float mx = e[0];
#pragma unroll
  for (int j=1;j<17;j++) mx = fmaxf(mx, e[j]);
  float den = 0.f;
#pragma unroll
  for (int j=0;j<17;j++){ e[j] = expf(e[j]-mx); den += e[j]; }
  float acc[F];
#pragma unroll
  for (int f=0;f<F;f++) acc[f]=0.f;
#pragma unroll
  for (int j=0;j<17;j++){
    const int sj = (j<16) ? __shfl(nb, j) : n;
    const float* hp = h + sj*CT + col;
    if constexpr (F==4){
      const float4 v = *(const float4*)hp;
      acc[0] += e[j]*v.x; acc[1] += e[j]*v.y; acc[2] += e[j]*v.z; acc[3] += e[j]*v.w;
    } else {
      const float2 v = *(const float2*)hp;
      acc[0] += e[j]*v.x; acc[1] += e[j]*v.y;
    }
  }
  const float inv = 1.f/den;
  if constexpr (F==4){
    float4 o;
    o.x = gelu_f(acc[0]*inv + bias[col+0]);
    o.y = gelu_f(acc[1]*inv + bias[col+1]);
    o.z = gelu_f(acc[2]*inv + bias[col+2]);
    o.w = gelu_f(acc[3]*inv + bias[col+3]);
    *(float4*)(out + n*CT + col) = o;
  } else {
    float2 o;
    o.x = gelu_f(acc[0]*inv + bias[col+0]);
    o.y = gelu_f(acc[1]*inv + bias[col+1]);
    *(float2*)(out + n*CT + col) = o;
  }
}

// ---------------- generic fp32 tiled GEMM: [M,KC] @ [KC,NC], BM=128 BN=64 BK=32 ----------------
template<int KC, int NC, bool BIAS, bool GELU>
__global__ __launch_bounds__(256) void gemm_k(const float* __restrict__ A, const float* __restrict__ B,
                                              const float* __restrict__ bias, float* __restrict__ C){
  __shared__ float Ast[32][132];   // A chunk transposed: Ast[k][row]
  __shared__ float Bs[32][64];
  const int t  = threadIdx.x;
  const int r0 = blockIdx.x*128;
  const int c0 = blockIdx.y*64;
  const int ty = t >> 4, tx = t & 15;
  const int ar = t >> 1, ac = (t & 1)*16;
  const int br = t >> 3, bc = (t & 7)*8;
  float acc[8][4];
#pragma unroll
  for (int i=0;i<8;i++)
#pragma unroll
    for (int j=0;j<4;j++) acc[i][j] = 0.f;

#pragma unroll 1
  for (int kc=0; kc<KC; kc+=32){
    const float* Ap = A + (size_t)(r0+ar)*KC + kc + ac;
    float4 av[4];
#pragma unroll
    for (int u=0;u<4;u++) av[u] = *(const float4*)(Ap + u*4);
#pragma unroll
    for (int u=0;u<4;u++){
      Ast[ac+u*4+0][ar] = av[u].x;
      Ast[ac+u*4+1][ar] = av[u].y;
      Ast[ac+u*4+2][ar] = av[u].z;
      Ast[ac+u*4+3][ar] = av[u].w;
    }
    const float* Bp = B + (size_t)(kc+br)*NC + c0 + bc;
    *(float4*)&Bs[br][bc]   = *(const float4*)Bp;
    *(float4*)&Bs[br][bc+4] = *(const float4*)(Bp+4);
    __syncthreads();
#pragma unroll
    for (int k=0;k<32;k++){
      const float4 a0 = *(const float4*)&Ast[k][ty*8];
      const float4 a1 = *(const float4*)&Ast[k][ty*8+4];
      const float4 bv = *(const float4*)&Bs[k][tx*4];
      const float avr[8] = {a0.x,a0.y,a0.z,a0.w,a1.x,a1.y,a1.z,a1.w};
      const float bbr[4] = {bv.x,bv.y,bv.z,bv.w};
#pragma unroll
      for (int i=0;i<8;i++)
#pragma unroll
        for (int j=0;j<4;j++)
          acc[i][j] += avr[i]*bbr[j];
    }
    __syncthreads();
  }
#pragma unroll
  for (int i=0;i<8;i++){
    const int r = r0 + ty*8 + i;
    float vv[4];
#pragma unroll
    for (int j=0;j<4;j++){
      float v = acc[i][j];
      if constexpr (BIAS) v += bias[c0 + tx*4 + j];
      if constexpr (GELU) v = gelu_f(v);
      vv[j] = v;
    }
    *(float4*)(C + (size_t)r*NC + c0 + tx*4) = make_float4(vv[0],vv[1],vv[2],vv[3]);
  }
}

// ---------------- final tiny GEMM: [NN,64] @ [64,6] + b ----------------
__global__ __launch_bounds__(256) void m3_k(const float* __restrict__ A, const float* __restrict__ W,
                                            const float* __restrict__ bias, float* __restrict__ out){
  __shared__ float Wl[64*6];
  __shared__ float bl[6];
  const int t = threadIdx.x;
  for (int i=t; i<384; i+=256) Wl[i] = W[i];
  if (t < 6) bl[t] = bias[t];
  __syncthreads();
  const int n = blockIdx.x*256 + t;
  const float* ap = A + n*64;
  float acc[6] = {0.f,0.f,0.f,0.f,0.f,0.f};
  for (int k=0;k<64;k+=4){
    const float4 v = *(const float4*)(ap+k);
    const float vr[4] = {v.x,v.y,v.z,v.w};
#pragma unroll
    for (int u=0;u<4;u++)
#pragma unroll
      for (int j=0;j<6;j++)
        acc[j] += vr[u]*Wl[(k+u)*6+j];
  }
#pragma unroll
  for (int j=0;j<6;j++) out[n*6+j] = acc[j] + bl[j];
}

extern "C" void kernel_launch(void* const* d_in, const int* in_sizes, int n_in,
                              void* d_out, int out_size, void* d_ws, size_t ws_size,
                              hipStream_t stream){
  (void)in_sizes; (void)n_in; (void)out_size; (void)ws_size;
  const float* x      = (const float*)d_in[0];
  const float* W1     = (const float*)d_in[1];
  const float* a_src1 = (const float*)d_in[2];
  const float* a_dst1 = (const float*)d_in[3];
  const float* b1     = (const float*)d_in[4];
  const float* W2     = (const float*)d_in[5];
  const float* a_src2 = (const float*)d_in[6];
  const float* a_dst2 = (const float*)d_in[7];
  const float* b2     = (const float*)d_in[8];
  const float* W3     = (const float*)d_in[9];
  const float* a_src3 = (const float*)d_in[10];
  const float* a_dst3 = (const float*)d_in[11];
  const float* b3     = (const float*)d_in[12];
  const float* res_W  = (const float*)d_in[13];
  const float* res_b  = (const float*)d_in[14];
  const float* m1_W   = (const float*)d_in[15];
  const float* m1_b   = (const float*)d_in[16];
  const float* m2_W   = (const float*)d_in[17];
  const float* m2_b   = (const float*)d_in[18];
  const float* m3_W   = (const float*)d_in[19];
  const float* m3_b   = (const float*)d_in[20];
  float* out = (float*)d_out;

  char* wsb = (char*)d_ws;
  int*   nbr = (int*)wsb;                                   // 1 MB
  float* H   = (float*)(wsb + (1u<<20));                    // 16 MB
  float* Y   = (float*)(wsb + (1u<<20) + (16u<<20));        // 16 MB
  float* ALS = (float*)(wsb + (1u<<20) + (32u<<20));        // 256 KB
  float* ALD = ALS + NN*4;

  knn_k<<<NN/4, 256, 0, stream>>>(x, nbr);

  // GAT layer 1: 6 -> 4x64
  gemm_in6<<<NN*64/256, 256, 0, stream>>>(x, W1, H);
  al_k<4,64><<<NN*4/256, 256, 0, stream>>>(H, a_src1, a_dst1, ALS, ALD);
  agg_k<4,64><<<NN/4, 256, 0, stream>>>(H, ALS, ALD, nbr, b1, Y);

  // GAT layer 2: 256 -> 4x64
  gemm_k<256,256,false,false><<<dim3(NN/128, 4), 256, 0, stream>>>(Y, W2, nullptr, H);
  al_k<4,64><<<NN*4/256, 256, 0, stream>>>(H, a_src2, a_dst2, ALS, ALD);
  agg_k<4,64><<<NN/4, 256, 0, stream>>>(H, ALS, ALD, nbr, b2, Y);

  // GAT layer 3: 256 -> 1x128
  gemm_k<256,128,false,false><<<dim3(NN/128, 2), 256, 0, stream>>>(Y, W3, nullptr, H);
  al_k<1,128><<<NN/256, 256, 0, stream>>>(H, a_src3, a_dst3, ALS, ALD);
  agg_k<1,128><<<NN/4, 256, 0, stream>>>(H, ALS, ALD, nbr, b3, Y);

  // residual + MLP
  res_k<<<NN*128/256, 256, 0, stream>>>(x, res_W, res_b, Y);
  gemm_k<128,128,true,true><<<dim3(NN/128, 2), 256, 0, stream>>>(Y, m1_W, m1_b, H);
  gemm_k<128,64,true,true><<<dim3(NN/128, 1), 256, 0, stream>>>(H, m2_W, m2_b, Y);
  m3_k<<<NN/256, 256, 0, stream>>>(Y, m3_W, m3_b, out);
}

// Round 2
// 355.985 us; speedup vs baseline: 1.2771x; 1.2771x over previous
//
#include <hip/hip_runtime.h>
#include <math.h>

#define NN 16384      // B*N total nodes
#define NPB 4096      // nodes per batch
#define KCAP 256      // survivor capacity (expected ~20-30 for Gaussian data)

__device__ __forceinline__ float gelu_f(float v){
  return 0.5f*v*(1.0f+erff(v*0.70710678118654752440f));
}

// ascending-by-lane bitonic sort of one u64 per lane across the 64-lane wave
__device__ __forceinline__ unsigned long long bsort64(unsigned long long v, int lane){
#pragma unroll
  for (int k=2;k<=64;k<<=1){
#pragma unroll
    for (int j=k>>1;j>0;j>>=1){
      const unsigned long long o = __shfl_xor(v, j);
      const bool keepMin = ((lane & k) == 0) == ((lane & j) == 0);
      const unsigned long long mn = v < o ? v : o;
      const unsigned long long mx = v < o ? o : v;
      v = keepMin ? mn : mx;
    }
  }
  return v;
}

// ---------------- per-node squared norms ----------------
__global__ __launch_bounds__(256) void sq_k(const float* __restrict__ x, float* __restrict__ sq){
  const int n = blockIdx.x*256 + threadIdx.x;
  const float* xr = x + (size_t)n*6;
  float s = 0.f;
#pragma unroll
  for (int d=0;d<6;d++) s += xr[d]*xr[d];
  sq[n] = s;
}

// ---------------- kNN v2: store keys in LDS, pivot via lane-min bitonic, ballot-compact, bitonic top-16 ----------------
__global__ __launch_bounds__(128) void knn_k(const float* __restrict__ x, const float* __restrict__ sq,
                                             int* __restrict__ nbr){
  __shared__ unsigned keybuf[2][4096];
  __shared__ int surv[2][KCAP];
  const int w = threadIdx.x >> 6, lane = threadIdx.x & 63;
  const int n = blockIdx.x*2 + w;
  const int base = n & ~(NPB-1);
  const float* xn = x + (size_t)n*6;
  const float x0=xn[0],x1=xn[1],x2=xn[2],x3=xn[3],x4=xn[4],x5=xn[5];
  const float sqn = sq[n];
  const int selfslot = n - base;

  // pass A: all 4096 keys -> LDS; track per-lane min
  unsigned lmk = 0xFFFFFFFFu; int lms = 0;
  for (int t=0;t<64;t++){
    const int slot = t*64 + lane;
    const float* xj = x + (size_t)(base + slot)*6;
    const float2 p0 = *(const float2*)(xj);
    const float2 p1 = *(const float2*)(xj+2);
    const float2 p2 = *(const float2*)(xj+4);
    const float sqj = sq[base+slot];
    const float dot = x0*p0.x + x1*p0.y + x2*p1.x + x3*p1.y + x4*p2.x + x5*p2.y;
    const float d2 = sqn + sqj - 2.0f*dot;
    unsigned u = __float_as_uint(d2);
    u = (u & 0x80000000u) ? ~u : (u | 0x80000000u);   // monotone float->uint
    if (slot == selfslot) u = 0xFFFFFFFFu;            // exclude self
    keybuf[w][slot] = u;
    if (u < lmk){ lmk = u; lms = slot; }
  }

  // pivot: 16th smallest of the 64 lane minima (upper bound on true 16th key)
  unsigned long long T = bsort64(((unsigned long long)lmk << 32) | (unsigned)lms, lane);
  T = __shfl(T, 15);

  // pass B: ballot-compact survivors (key <= T)
  int cnt = 0;
  for (int t=0;t<64;t++){
    const int slot = t*64 + lane;
    const unsigned u = keybuf[w][slot];
    const unsigned long long key = ((unsigned long long)u << 32) | (unsigned)slot;
    const bool p = key <= T;
    const unsigned long long b = __ballot(p);
    if (p){
      const int pos = cnt + (int)__popcll(b & ((1ull << lane) - 1ull));
      if (pos < KCAP) surv[w][pos] = slot;
    }
    cnt += (int)__popcll(b);
  }
  if (cnt > KCAP) cnt = KCAP;

  // final: bitonic sort survivors (chunks of 64, keep-low merge); lanes 0..15 = top-16
  unsigned long long vbest;
  {
    unsigned long long v = ~0ull;
    if (lane < cnt){
      const int s = surv[w][lane];
      v = ((unsigned long long)keybuf[w][s] << 32) | (unsigned)s;
    }
    vbest = bsort64(v, lane);
  }
  for (int c=1; c*64 < cnt; ++c){
    const int i = c*64 + lane;
    unsigned long long v = ~0ull;
    if (i < cnt){
      const int s = surv[w][i];
      v = ((unsigned long long)keybuf[w][s] << 32) | (unsigned)s;
    }
    v = bsort64(v, lane);
    const unsigned long long r = __shfl(v, 63-lane);
    vbest = vbest < r ? vbest : r;     // bitonic sequence of the 64 smallest
#pragma unroll
    for (int j=32;j>0;j>>=1){          // cleanup merge, ascending
      const unsigned long long o = __shfl_xor(vbest, j);
      const bool keepMin = (lane & j) == 0;
      const unsigned long long mn = vbest < o ? vbest : o;
      const unsigned long long mx = vbest < o ? o : vbest;
      vbest = keepMin ? mn : mx;
    }
  }
  if (lane < 16) nbr[n*16 + lane] = base + (int)(vbest & 0xFFFFFFFFull);
}

// ---------------- layer-1 GEMM: x[NN,6] @ W1[6,256] ----------------
__global__ __launch_bounds__(256) void gemm_in6(const float* __restrict__ x, const float* __restrict__ W,
                                                float* __restrict__ h){
  const int t = blockIdx.x*256 + threadIdx.x;  // over NN*64
  const int n = t >> 6, cg = t & 63;
  const float* xr = x + n*6;
  float xv[6];
#pragma unroll
  for (int d=0; d<6; d++) xv[d] = xr[d];
  float4 acc = make_float4(0.f,0.f,0.f,0.f);
#pragma unroll
  for (int d=0; d<6; d++){
    const float4 wv = *(const float4*)(W + d*256 + cg*4);
    acc.x += xv[d]*wv.x; acc.y += xv[d]*wv.y; acc.z += xv[d]*wv.z; acc.w += xv[d]*wv.w;
  }
  *(float4*)(h + n*256 + cg*4) = acc;
}

// ---------------- residual: y[NN,128] += x@res_W + res_b ----------------
__global__ __launch_bounds__(256) void res_k(const float* __restrict__ x, const float* __restrict__ W,
                                             const float* __restrict__ b, float* __restrict__ y){
  const int t = blockIdx.x*256 + threadIdx.x;  // over NN*128
  const int n = t >> 7, c = t & 127;
  const float* xr = x + n*6;
  float acc = b[c];
#pragma unroll
  for (int d=0; d<6; d++) acc += xr[d]*W[d*128 + c];
  y[t] += acc;
}

// ---------------- attention logits: als/ald [NN,HEADS] ----------------
template<int HEADS, int C>
__global__ __launch_bounds__(256) void al_k(const float* __restrict__ h, const float* __restrict__ asrc,
                                            const float* __restrict__ adst, float* __restrict__ als,
                                            float* __restrict__ ald){
  const int t = blockIdx.x*256 + threadIdx.x;  // over NN*HEADS
  const int n = t / HEADS, hd = t % HEADS;
  const float* hp = h + (n*HEADS + hd)*C;
  const float* ap = asrc + hd*C;
  const float* dp = adst + hd*C;
  float s=0.f, d=0.f;
#pragma unroll 4
  for (int c=0;c<C;c+=4){
    const float4 v = *(const float4*)(hp+c);
    const float4 a = *(const float4*)(ap+c);
    const float4 b = *(const float4*)(dp+c);
    s += v.x*a.x + v.y*a.y + v.z*a.z + v.w*a.w;
    d += v.x*b.x + v.y*b.y + v.z*b.z + v.w*b.w;
  }
  als[t] = s; ald[t] = d;
}

// ---------------- GAT aggregation: one wave per node, 17-way softmax gather ----------------
template<int HEADS, int C>
__global__ __launch_bounds__(256) void agg_k(const float* __restrict__ h, const float* __restrict__ als,
                                             const float* __restrict__ ald, const int* __restrict__ nbr,
                                             const float* __restrict__ bias, float* __restrict__ out){
  constexpr int CT = HEADS*C;
  constexpr int F  = CT/64;
  const int w = threadIdx.x >> 6, lane = threadIdx.x & 63;
  const int n = blockIdx.x*4 + w;
  const int head = (lane*F)/C;
  const int col  = lane*F;
  const int nb = nbr[n*16 + (lane & 15)];
  const float aldn = ald[n*HEADS + head];
  float e[17];
#pragma unroll
  for (int j=0;j<17;j++){
    const int sj = (j<16) ? __shfl(nb, j) : n;
    const float v = als[sj*HEADS + head] + aldn;
    e[j] = v > 0.f ? v : 0.2f*v;
  }
  float mx = e[0];
#pragma unroll
  for (int j=1;j<17;j++) mx = fmaxf(mx, e[j]);
  float den = 0.f;
#pragma unroll
  for (int j=0;j<17;j++){ e[j] = expf(e[j]-mx); den += e[j]; }
  float acc[F];
#pragma unroll
  for (int f=0;f<F;f++) acc[f]=0.f;
#pragma unroll
  for (int j=0;j<17;j++){
    const int sj = (j<16) ? __shfl(nb, j) : n;
    const float* hp = h + sj*CT + col;
    if constexpr (F==4){
      const float4 v = *(const float4*)hp;
      acc[0] += e[j]*v.x; acc[1] += e[j]*v.y; acc[2] += e[j]*v.z; acc[3] += e[j]*v.w;
    } else {
      const float2 v = *(const float2*)hp;
      acc[0] += e[j]*v.x; acc[1] += e[j]*v.y;
    }
  }
  const float inv = 1.f/den;
  if constexpr (F==4){
    float4 o;
    o.x = gelu_f(acc[0]*inv + bias[col+0]);
    o.y = gelu_f(acc[1]*inv + bias[col+1]);
    o.z = gelu_f(acc[2]*inv + bias[col+2]);
    o.w = gelu_f(acc[3]*inv + bias[col+3]);
    *(float4*)(out + n*CT + col) = o;
  } else {
    float2 o;
    o.x = gelu_f(acc[0]*inv + bias[col+0]);
    o.y = gelu_f(acc[1]*inv + bias[col+1]);
    *(float2*)(out + n*CT + col) = o;
  }
}

// ---------------- generic fp32 tiled GEMM: [M,KC] @ [KC,NC], BM=128 BN=64 BK=32 ----------------
template<int KC, int NC, bool BIAS, bool GELU>
__global__ __launch_bounds__(256) void gemm_k(const float* __restrict__ A, const float* __restrict__ B,
                                              const float* __restrict__ bias, float* __restrict__ C){
  __shared__ float Ast[32][132];   // A chunk transposed: Ast[k][row]
  __shared__ float Bs[32][64];
  const int t  = threadIdx.x;
  const int r0 = blockIdx.x*128;
  const int c0 = blockIdx.y*64;
  const int ty = t >> 4, tx = t & 15;
  const int ar = t >> 1, ac = (t & 1)*16;
  const int br = t >> 3, bc = (t & 7)*8;
  float acc[8][4];
#pragma unroll
  for (int i=0;i<8;i++)
#pragma unroll
    for (int j=0;j<4;j++) acc[i][j] = 0.f;

#pragma unroll 1
  for (int kc=0; kc<KC; kc+=32){
    const float* Ap = A + (size_t)(r0+ar)*KC + kc + ac;
    float4 av[4];
#pragma unroll
    for (int u=0;u<4;u++) av[u] = *(const float4*)(Ap + u*4);
#pragma unroll
    for (int u=0;u<4;u++){
      Ast[ac+u*4+0][ar] = av[u].x;
      Ast[ac+u*4+1][ar] = av[u].y;
      Ast[ac+u*4+2][ar] = av[u].z;
      Ast[ac+u*4+3][ar] = av[u].w;
    }
    const float* Bp = B + (size_t)(kc+br)*NC + c0 + bc;
    *(float4*)&Bs[br][bc]   = *(const float4*)Bp;
    *(float4*)&Bs[br][bc+4] = *(const float4*)(Bp+4);
    __syncthreads();
#pragma unroll
    for (int k=0;k<32;k++){
      const float4 a0 = *(const float4*)&Ast[k][ty*8];
      const float4 a1 = *(const float4*)&Ast[k][ty*8+4];
      const float4 bv = *(const float4*)&Bs[k][tx*4];
      const float avr[8] = {a0.x,a0.y,a0.z,a0.w,a1.x,a1.y,a1.z,a1.w};
      const float bbr[4] = {bv.x,bv.y,bv.z,bv.w};
#pragma unroll
      for (int i=0;i<8;i++)
#pragma unroll
        for (int j=0;j<4;j++)
          acc[i][j] += avr[i]*bbr[j];
    }
    __syncthreads();
  }
#pragma unroll
  for (int i=0;i<8;i++){
    const int r = r0 + ty*8 + i;
    float vv[4];
#pragma unroll
    for (int j=0;j<4;j++){
      float v = acc[i][j];
      if constexpr (BIAS) v += bias[c0 + tx*4 + j];
      if constexpr (GELU) v = gelu_f(v);
      vv[j] = v;
    }
    *(float4*)(C + (size_t)r*NC + c0 + tx*4) = make_float4(vv[0],vv[1],vv[2],vv[3]);
  }
}

// ---------------- final tiny GEMM: [NN,64] @ [64,6] + b ----------------
__global__ __launch_bounds__(256) void m3_k(const float* __restrict__ A, const float* __restrict__ W,
                                            const float* __restrict__ bias, float* __restrict__ out){
  __shared__ float Wl[64*6];
  __shared__ float bl[6];
  const int t = threadIdx.x;
  for (int i=t; i<384; i+=256) Wl[i] = W[i];
  if (t < 6) bl[t] = bias[t];
  __syncthreads();
  const int n = blockIdx.x*256 + t;
  const float* ap = A + n*64;
  float acc[6] = {0.f,0.f,0.f,0.f,0.f,0.f};
  for (int k=0;k<64;k+=4){
    const float4 v = *(const float4*)(ap+k);
    const float vr[4] = {v.x,v.y,v.z,v.w};
#pragma unroll
    for (int u=0;u<4;u++)
#pragma unroll
      for (int j=0;j<6;j++)
        acc[j] += vr[u]*Wl[(k+u)*6+j];
  }
#pragma unroll
  for (int j=0;j<6;j++) out[n*6+j] = acc[j] + bl[j];
}

extern "C" void kernel_launch(void* const* d_in, const int* in_sizes, int n_in,
                              void* d_out, int out_size, void* d_ws, size_t ws_size,
                              hipStream_t stream){
  (void)in_sizes; (void)n_in; (void)out_size; (void)ws_size;
  const float* x      = (const float*)d_in[0];
  const float* W1     = (const float*)d_in[1];
  const float* a_src1 = (const float*)d_in[2];
  const float* a_dst1 = (const float*)d_in[3];
  const float* b1     = (const float*)d_in[4];
  const float* W2     = (const float*)d_in[5];
  const float* a_src2 = (const float*)d_in[6];
  const float* a_dst2 = (const float*)d_in[7];
  const float* b2     = (const float*)d_in[8];
  const float* W3     = (const float*)d_in[9];
  const float* a_src3 = (const float*)d_in[10];
  const float* a_dst3 = (const float*)d_in[11];
  const float* b3     = (const float*)d_in[12];
  const float* res_W  = (const float*)d_in[13];
  const float* res_b  = (const float*)d_in[14];
  const float* m1_W   = (const float*)d_in[15];
  const float* m1_b   = (const float*)d_in[16];
  const float* m2_W   = (const float*)d_in[17];
  const float* m2_b   = (const float*)d_in[18];
  const float* m3_W   = (const float*)d_in[19];
  const float* m3_b   = (const float*)d_in[20];
  float* out = (float*)d_out;

  char* wsb = (char*)d_ws;
  int*   nbr = (int*)wsb;                                   // 1 MB
  float* H   = (float*)(wsb + (1u<<20));                    // 16 MB
  float* Y   = (float*)(wsb + (1u<<20) + (16u<<20));        // 16 MB
  float* ALS = (float*)(wsb + (1u<<20) + (32u<<20));        // 256 KB
  float* ALD = ALS + NN*4;                                  // 256 KB
  float* SQ  = (float*)(wsb + (1u<<20) + (32u<<20) + (512u<<10)); // 64 KB

  sq_k<<<NN/256, 256, 0, stream>>>(x, SQ);
  knn_k<<<NN/2, 128, 0, stream>>>(x, SQ, nbr);

  // GAT layer 1: 6 -> 4x64
  gemm_in6<<<NN*64/256, 256, 0, stream>>>(x, W1, H);
  al_k<4,64><<<NN*4/256, 256, 0, stream>>>(H, a_src1, a_dst1, ALS, ALD);
  agg_k<4,64><<<NN/4, 256, 0, stream>>>(H, ALS, ALD, nbr, b1, Y);

  // GAT layer 2: 256 -> 4x64
  gemm_k<256,256,false,false><<<dim3(NN/128, 4), 256, 0, stream>>>(Y, W2, nullptr, H);
  al_k<4,64><<<NN*4/256, 256, 0, stream>>>(H, a_src2, a_dst2, ALS, ALD);
  agg_k<4,64><<<NN/4, 256, 0, stream>>>(H, ALS, ALD, nbr, b2, Y);

  // GAT layer 3: 256 -> 1x128
  gemm_k<256,128,false,false><<<dim3(NN/128, 2), 256, 0, stream>>>(Y, W3, nullptr, H);
  al_k<1,128><<<NN/256, 256, 0, stream>>>(H, a_src3, a_dst3, ALS, ALD);
  agg_k<1,128><<<NN/4, 256, 0, stream>>>(H, ALS, ALD, nbr, b3, Y);

  // residual + MLP
  res_k<<<NN*128/256, 256, 0, stream>>>(x, res_W, res_b, Y);
  gemm_k<128,128,true,true><<<dim3(NN/128, 2), 256, 0, stream>>>(Y, m1_W, m1_b, H);
  gemm_k<128,64,true,true><<<dim3(NN/128, 1), 256, 0, stream>>>(H, m2_W, m2_b, Y);
  m3_k<<<NN/256, 256, 0, stream>>>(Y, m3_W, m3_b, out);
}

// Round 3
// 301.652 us; speedup vs baseline: 1.5071x; 1.1801x over previous
//
#include <hip/hip_runtime.h>
#include <math.h>

#define NN 16384      // B*N total nodes
#define NPB 4096      // nodes per batch
#define KCAP 256      // survivor capacity per wave
#define TS 1024       // kNN candidate tile size

__device__ __forceinline__ float gelu_f(float v){
  return 0.5f*v*(1.0f+erff(v*0.70710678118654752440f));
}

// ascending-by-lane bitonic sort of one u64 per lane across the 64-lane wave
__device__ __forceinline__ unsigned long long bsort64(unsigned long long v, int lane){
#pragma unroll
  for (int k=2;k<=64;k<<=1){
#pragma unroll
    for (int j=k>>1;j>0;j>>=1){
      const unsigned long long o = __shfl_xor(v, j);
      const bool keepMin = ((lane & k) == 0) == ((lane & j) == 0);
      const unsigned long long mn = v < o ? v : o;
      const unsigned long long mx = v < o ? o : v;
      v = keepMin ? mn : mx;
    }
  }
  return v;
}

// ascending-by-lane bitonic sort of one u32 per lane
__device__ __forceinline__ unsigned bsort32(unsigned v, int lane){
#pragma unroll
  for (int k=2;k<=64;k<<=1){
#pragma unroll
    for (int j=k>>1;j>0;j>>=1){
      const unsigned o = __shfl_xor(v, j);
      const bool keepMin = ((lane & k) == 0) == ((lane & j) == 0);
      const unsigned mn = v < o ? v : o;
      const unsigned mx = v < o ? o : v;
      v = keepMin ? mn : mx;
    }
  }
  return v;
}

// ---------------- pack: x[NN,6] -> PA[NN]={x0..x3}, PB[NN]={x4,x5,sq,0} ----------------
__global__ __launch_bounds__(256) void pack_k(const float* __restrict__ x,
                                              float4* __restrict__ PA, float4* __restrict__ PB){
  const int n = blockIdx.x*256 + threadIdx.x;
  const float* xr = x + (size_t)n*6;
  const float x0=xr[0],x1=xr[1],x2=xr[2],x3=xr[3],x4=xr[4],x5=xr[5];
  const float sq = x0*x0+x1*x1+x2*x2+x3*x3+x4*x4+x5*x5;
  PA[n] = make_float4(x0,x1,x2,x3);
  PB[n] = make_float4(x4,x5,sq,0.f);
}

// ---------------- kNN v3: block=4 waves/4 queries, LDS candidate tiles, register keys,
//                  per-tile pivot (16th lane-min) + ballot compact, exact u64 final merge --------
__global__ __launch_bounds__(256) void knn_k(const float4* __restrict__ PA, const float4* __restrict__ PB,
                                             int* __restrict__ nbr){
  __shared__ float4 A4[TS];
  __shared__ float4 B4[TS];
  __shared__ unsigned skey[4][KCAP];
  __shared__ unsigned sslot[4][KCAP];
  const int t = threadIdx.x, w = t >> 6, lane = t & 63;
  const int n = blockIdx.x*4 + w;
  const int base = n & ~(NPB-1);
  const float4 qa = PA[n];
  const float4 qb = PB[n];
  const float sqn = qb.z;
  const int selfslot = n - base;

  int cnt = 0;
#pragma unroll 1
  for (int tile=0; tile<NPB/TS; ++tile){
    const int tb = tile*TS;
    __syncthreads();   // all waves done reading previous tile
    for (int i=t; i<TS; i+=256){
      A4[i] = PA[base+tb+i];
      B4[i] = PB[base+tb+i];
    }
    __syncthreads();

    unsigned keys[16];
    unsigned lmk = 0xFFFFFFFFu;
#pragma unroll
    for (int it=0; it<16; ++it){
      const int s = it*64 + lane;
      const float4 a = A4[s];
      const float4 b = B4[s];
      const float dot = qa.x*a.x + qa.y*a.y + qa.z*a.z + qa.w*a.w + qb.x*b.x + qb.y*b.y;
      const float d2 = sqn + b.z - 2.0f*dot;
      unsigned u = __float_as_uint(d2);
      u = (u & 0x80000000u) ? ~u : (u | 0x80000000u);   // monotone float->uint
      if (tb + s == selfslot) u = 0xFFFFFFFFu;          // exclude self
      keys[it] = u;
      lmk = u < lmk ? u : lmk;
    }

    // pivot: 16th smallest of the 64 lane minima (upper bound on tile's 16th key)
    unsigned T = bsort32(lmk, lane);
    T = __shfl(T, 15);

    // ballot-compact survivors (key <= T) into per-wave list
#pragma unroll
    for (int it=0; it<16; ++it){
      const bool p = keys[it] <= T;
      const unsigned long long bb = __ballot(p);
      if (p){
        const int pos = cnt + (int)__popcll(bb & ((1ull << lane) - 1ull));
        if (pos < KCAP){ skey[w][pos] = keys[it]; sslot[w][pos] = (unsigned)(tb + it*64 + lane); }
      }
      cnt += (int)__popcll(bb);
    }
  }
  if (cnt > KCAP) cnt = KCAP;

  // final: exact top-16 over survivors, chunked keep-low bitonic merge (u64 = key||slot)
  unsigned long long vbest;
  {
    unsigned long long v = ~0ull;
    if (lane < cnt) v = ((unsigned long long)skey[w][lane] << 32) | sslot[w][lane];
    vbest = bsort64(v, lane);
  }
  for (int c=1; c*64 < cnt; ++c){
    const int i = c*64 + lane;
    unsigned long long v = ~0ull;
    if (i < cnt) v = ((unsigned long long)skey[w][i] << 32) | sslot[w][i];
    v = bsort64(v, lane);
    const unsigned long long r = __shfl(v, 63-lane);
    vbest = vbest < r ? vbest : r;     // bitonic sequence of the 64 smallest
#pragma unroll
    for (int j=32;j>0;j>>=1){          // cleanup merge, ascending
      const unsigned long long o = __shfl_xor(vbest, j);
      const bool keepMin = (lane & j) == 0;
      const unsigned long long mn = vbest < o ? vbest : o;
      const unsigned long long mx = vbest < o ? o : vbest;
      vbest = keepMin ? mn : mx;
    }
  }
  if (lane < 16) nbr[n*16 + lane] = base + (int)(vbest & 0xFFFFFFFFull);
}

// ---------------- layer-1 GEMM: x[NN,6] @ W1[6,256] ----------------
__global__ __launch_bounds__(256) void gemm_in6(const float* __restrict__ x, const float* __restrict__ W,
                                                float* __restrict__ h){
  const int t = blockIdx.x*256 + threadIdx.x;  // over NN*64
  const int n = t >> 6, cg = t & 63;
  const float* xr = x + n*6;
  float xv[6];
#pragma unroll
  for (int d=0; d<6; d++) xv[d] = xr[d];
  float4 acc = make_float4(0.f,0.f,0.f,0.f);
#pragma unroll
  for (int d=0; d<6; d++){
    const float4 wv = *(const float4*)(W + d*256 + cg*4);
    acc.x += xv[d]*wv.x; acc.y += xv[d]*wv.y; acc.z += xv[d]*wv.z; acc.w += xv[d]*wv.w;
  }
  *(float4*)(h + n*256 + cg*4) = acc;
}

// ---------------- residual: y[NN,128] += x@res_W + res_b ----------------
__global__ __launch_bounds__(256) void res_k(const float* __restrict__ x, const float* __restrict__ W,
                                             const float* __restrict__ b, float* __restrict__ y){
  const int t = blockIdx.x*256 + threadIdx.x;  // over NN*128
  const int n = t >> 7, c = t & 127;
  const float* xr = x + n*6;
  float acc = b[c];
#pragma unroll
  for (int d=0; d<6; d++) acc += xr[d]*W[d*128 + c];
  y[t] += acc;
}

// ---------------- attention logits: als/ald [NN,HEADS] ----------------
template<int HEADS, int C>
__global__ __launch_bounds__(256) void al_k(const float* __restrict__ h, const float* __restrict__ asrc,
                                            const float* __restrict__ adst, float* __restrict__ als,
                                            float* __restrict__ ald){
  const int t = blockIdx.x*256 + threadIdx.x;  // over NN*HEADS
  const int n = t / HEADS, hd = t % HEADS;
  const float* hp = h + (n*HEADS + hd)*C;
  const float* ap = asrc + hd*C;
  const float* dp = adst + hd*C;
  float s=0.f, d=0.f;
#pragma unroll 4
  for (int c=0;c<C;c+=4){
    const float4 v = *(const float4*)(hp+c);
    const float4 a = *(const float4*)(ap+c);
    const float4 b = *(const float4*)(dp+c);
    s += v.x*a.x + v.y*a.y + v.z*a.z + v.w*a.w;
    d += v.x*b.x + v.y*b.y + v.z*b.z + v.w*b.w;
  }
  als[t] = s; ald[t] = d;
}

// ---------------- GAT aggregation: one wave per node, 17-way softmax gather ----------------
template<int HEADS, int C>
__global__ __launch_bounds__(256) void agg_k(const float* __restrict__ h, const float* __restrict__ als,
                                             const float* __restrict__ ald, const int* __restrict__ nbr,
                                             const float* __restrict__ bias, float* __restrict__ out){
  constexpr int CT = HEADS*C;
  constexpr int F  = CT/64;
  const int w = threadIdx.x >> 6, lane = threadIdx.x & 63;
  const int n = blockIdx.x*4 + w;
  const int head = (lane*F)/C;
  const int col  = lane*F;
  const int nb = nbr[n*16 + (lane & 15)];
  const float aldn = ald[n*HEADS + head];
  float e[17];
#pragma unroll
  for (int j=0;j<17;j++){
    const int sj = (j<16) ? __shfl(nb, j) : n;
    const float v = als[sj*HEADS + head] + aldn;
    e[j] = v > 0.f ? v : 0.2f*v;
  }
  float mx = e[0];
#pragma unroll
  for (int j=1;j<17;j++) mx = fmaxf(mx, e[j]);
  float den = 0.f;
#pragma unroll
  for (int j=0;j<17;j++){ e[j] = expf(e[j]-mx); den += e[j]; }
  float acc[F];
#pragma unroll
  for (int f=0;f<F;f++) acc[f]=0.f;
#pragma unroll
  for (int j=0;j<17;j++){
    const int sj = (j<16) ? __shfl(nb, j) : n;
    const float* hp = h + sj*CT + col;
    if constexpr (F==4){
      const float4 v = *(const float4*)hp;
      acc[0] += e[j]*v.x; acc[1] += e[j]*v.y; acc[2] += e[j]*v.z; acc[3] += e[j]*v.w;
    } else {
      const float2 v = *(const float2*)hp;
      acc[0] += e[j]*v.x; acc[1] += e[j]*v.y;
    }
  }
  const float inv = 1.f/den;
  if constexpr (F==4){
    float4 o;
    o.x = gelu_f(acc[0]*inv + bias[col+0]);
    o.y = gelu_f(acc[1]*inv + bias[col+1]);
    o.z = gelu_f(acc[2]*inv + bias[col+2]);
    o.w = gelu_f(acc[3]*inv + bias[col+3]);
    *(float4*)(out + n*CT + col) = o;
  } else {
    float2 o;
    o.x = gelu_f(acc[0]*inv + bias[col+0]);
    o.y = gelu_f(acc[1]*inv + bias[col+1]);
    *(float2*)(out + n*CT + col) = o;
  }
}

// ---------------- generic fp32 tiled GEMM: [M,KC] @ [KC,NC], BM=128 BN=64 BK=32 ----------------
template<int KC, int NC, bool BIAS, bool GELU>
__global__ __launch_bounds__(256) void gemm_k(const float* __restrict__ A, const float* __restrict__ B,
                                              const float* __restrict__ bias, float* __restrict__ C){
  __shared__ float Ast[32][132];   // A chunk transposed: Ast[k][row]
  __shared__ float Bs[32][64];
  const int t  = threadIdx.x;
  const int r0 = blockIdx.x*128;
  const int c0 = blockIdx.y*64;
  const int ty = t >> 4, tx = t & 15;
  const int ar = t >> 1, ac = (t & 1)*16;
  const int br = t >> 3, bc = (t & 7)*8;
  float acc[8][4];
#pragma unroll
  for (int i=0;i<8;i++)
#pragma unroll
    for (int j=0;j<4;j++) acc[i][j] = 0.f;

#pragma unroll 1
  for (int kc=0; kc<KC; kc+=32){
    const float* Ap = A + (size_t)(r0+ar)*KC + kc + ac;
    float4 av[4];
#pragma unroll
    for (int u=0;u<4;u++) av[u] = *(const float4*)(Ap + u*4);
#pragma unroll
    for (int u=0;u<4;u++){
      Ast[ac+u*4+0][ar] = av[u].x;
      Ast[ac+u*4+1][ar] = av[u].y;
      Ast[ac+u*4+2][ar] = av[u].z;
      Ast[ac+u*4+3][ar] = av[u].w;
    }
    const float* Bp = B + (size_t)(kc+br)*NC + c0 + bc;
    *(float4*)&Bs[br][bc]   = *(const float4*)Bp;
    *(float4*)&Bs[br][bc+4] = *(const float4*)(Bp+4);
    __syncthreads();
#pragma unroll
    for (int k=0;k<32;k++){
      const float4 a0 = *(const float4*)&Ast[k][ty*8];
      const float4 a1 = *(const float4*)&Ast[k][ty*8+4];
      const float4 bv = *(const float4*)&Bs[k][tx*4];
      const float avr[8] = {a0.x,a0.y,a0.z,a0.w,a1.x,a1.y,a1.z,a1.w};
      const float bbr[4] = {bv.x,bv.y,bv.z,bv.w};
#pragma unroll
      for (int i=0;i<8;i++)
#pragma unroll
        for (int j=0;j<4;j++)
          acc[i][j] += avr[i]*bbr[j];
    }
    __syncthreads();
  }
#pragma unroll
  for (int i=0;i<8;i++){
    const int r = r0 + ty*8 + i;
    float vv[4];
#pragma unroll
    for (int j=0;j<4;j++){
      float v = acc[i][j];
      if constexpr (BIAS) v += bias[c0 + tx*4 + j];
      if constexpr (GELU) v = gelu_f(v);
      vv[j] = v;
    }
    *(float4*)(C + (size_t)r*NC + c0 + tx*4) = make_float4(vv[0],vv[1],vv[2],vv[3]);
  }
}

// ---------------- final tiny GEMM: [NN,64] @ [64,6] + b ----------------
__global__ __launch_bounds__(256) void m3_k(const float* __restrict__ A, const float* __restrict__ W,
                                            const float* __restrict__ bias, float* __restrict__ out){
  __shared__ float Wl[64*6];
  __shared__ float bl[6];
  const int t = threadIdx.x;
  for (int i=t; i<384; i+=256) Wl[i] = W[i];
  if (t < 6) bl[t] = bias[t];
  __syncthreads();
  const int n = blockIdx.x*256 + t;
  const float* ap = A + n*64;
  float acc[6] = {0.f,0.f,0.f,0.f,0.f,0.f};
  for (int k=0;k<64;k+=4){
    const float4 v = *(const float4*)(ap+k);
    const float vr[4] = {v.x,v.y,v.z,v.w};
#pragma unroll
    for (int u=0;u<4;u++)
#pragma unroll
      for (int j=0;j<6;j++)
        acc[j] += vr[u]*Wl[(k+u)*6+j];
  }
#pragma unroll
  for (int j=0;j<6;j++) out[n*6+j] = acc[j] + bl[j];
}

extern "C" void kernel_launch(void* const* d_in, const int* in_sizes, int n_in,
                              void* d_out, int out_size, void* d_ws, size_t ws_size,
                              hipStream_t stream){
  (void)in_sizes; (void)n_in; (void)out_size; (void)ws_size;
  const float* x      = (const float*)d_in[0];
  const float* W1     = (const float*)d_in[1];
  const float* a_src1 = (const float*)d_in[2];
  const float* a_dst1 = (const float*)d_in[3];
  const float* b1     = (const float*)d_in[4];
  const float* W2     = (const float*)d_in[5];
  const float* a_src2 = (const float*)d_in[6];
  const float* a_dst2 = (const float*)d_in[7];
  const float* b2     = (const float*)d_in[8];
  const float* W3     = (const float*)d_in[9];
  const float* a_src3 = (const float*)d_in[10];
  const float* a_dst3 = (const float*)d_in[11];
  const float* b3     = (const float*)d_in[12];
  const float* res_W  = (const float*)d_in[13];
  const float* res_b  = (const float*)d_in[14];
  const float* m1_W   = (const float*)d_in[15];
  const float* m1_b   = (const float*)d_in[16];
  const float* m2_W   = (const float*)d_in[17];
  const float* m2_b   = (const float*)d_in[18];
  const float* m3_W   = (const float*)d_in[19];
  const float* m3_b   = (const float*)d_in[20];
  float* out = (float*)d_out;

  char* wsb = (char*)d_ws;
  int*   nbr = (int*)wsb;                                   // 1 MB
  float* H   = (float*)(wsb + (1u<<20));                    // 16 MB
  float* Y   = (float*)(wsb + (1u<<20) + (16u<<20));        // 16 MB
  float* ALS = (float*)(wsb + (1u<<20) + (32u<<20));        // 256 KB
  float* ALD = ALS + NN*4;                                  // 256 KB
  float4* PA = (float4*)(wsb + (1u<<20) + (32u<<20) + (512u<<10)); // 256 KB
  float4* PB = PA + NN;                                            // 256 KB

  pack_k<<<NN/256, 256, 0, stream>>>(x, PA, PB);
  knn_k<<<NN/4, 256, 0, stream>>>(PA, PB, nbr);

  // GAT layer 1: 6 -> 4x64
  gemm_in6<<<NN*64/256, 256, 0, stream>>>(x, W1, H);
  al_k<4,64><<<NN*4/256, 256, 0, stream>>>(H, a_src1, a_dst1, ALS, ALD);
  agg_k<4,64><<<NN/4, 256, 0, stream>>>(H, ALS, ALD, nbr, b1, Y);

  // GAT layer 2: 256 -> 4x64
  gemm_k<256,256,false,false><<<dim3(NN/128, 4), 256, 0, stream>>>(Y, W2, nullptr, H);
  al_k<4,64><<<NN*4/256, 256, 0, stream>>>(H, a_src2, a_dst2, ALS, ALD);
  agg_k<4,64><<<NN/4, 256, 0, stream>>>(H, ALS, ALD, nbr, b2, Y);

  // GAT layer 3: 256 -> 1x128
  gemm_k<256,128,false,false><<<dim3(NN/128, 2), 256, 0, stream>>>(Y, W3, nullptr, H);
  al_k<1,128><<<NN/256, 256, 0, stream>>>(H, a_src3, a_dst3, ALS, ALD);
  agg_k<1,128><<<NN/4, 256, 0, stream>>>(H, ALS, ALD, nbr, b3, Y);

  // residual + MLP
  res_k<<<NN*128/256, 256, 0, stream>>>(x, res_W, res_b, Y);
  gemm_k<128,128,true,true><<<dim3(NN/128, 2), 256, 0, stream>>>(Y, m1_W, m1_b, H);
  gemm_k<128,64,true,true><<<dim3(NN/128, 1), 256, 0, stream>>>(H, m2_W, m2_b, Y);
  m3_k<<<NN/256, 256, 0, stream>>>(Y, m3_W, m3_b, out);
}

// Round 4
// 287.331 us; speedup vs baseline: 1.5822x; 1.0498x over previous
//
#include <hip/hip_runtime.h>
#include <math.h>

#define NN 16384      // B*N total nodes
#define NPB 4096      // nodes per batch
#define KCAP 128      // survivor capacity per wave (expected ~20 global)
#define TS 1024       // kNN candidate tile size

__device__ __forceinline__ float gelu_f(float v){
  return 0.5f*v*(1.0f+erff(v*0.70710678118654752440f));
}

// ascending-by-lane bitonic sort of one u64 per lane across the 64-lane wave
__device__ __forceinline__ unsigned long long bsort64(unsigned long long v, int lane){
#pragma unroll
  for (int k=2;k<=64;k<<=1){
#pragma unroll
    for (int j=k>>1;j>0;j>>=1){
      const unsigned long long o = __shfl_xor(v, j);
      const bool keepMin = ((lane & k) == 0) == ((lane & j) == 0);
      const unsigned long long mn = v < o ? v : o;
      const unsigned long long mx = v < o ? o : v;
      v = keepMin ? mn : mx;
    }
  }
  return v;
}

// ascending-by-lane bitonic sort of one u32 per lane
__device__ __forceinline__ unsigned bsort32(unsigned v, int lane){
#pragma unroll
  for (int k=2;k<=64;k<<=1){
#pragma unroll
    for (int j=k>>1;j>0;j>>=1){
      const unsigned o = __shfl_xor(v, j);
      const bool keepMin = ((lane & k) == 0) == ((lane & j) == 0);
      const unsigned mn = v < o ? v : o;
      const unsigned mx = v < o ? o : v;
      v = keepMin ? mn : mx;
    }
  }
  return v;
}

// ---------------- pack: x[NN,6] -> PA[NN]={x0..x3}, PB[NN]={x4,x5,sq,0} ----------------
__global__ __launch_bounds__(256) void pack_k(const float* __restrict__ x,
                                              float4* __restrict__ PA, float4* __restrict__ PB){
  const int n = blockIdx.x*256 + threadIdx.x;
  const float* xr = x + (size_t)n*6;
  const float x0=xr[0],x1=xr[1],x2=xr[2],x3=xr[3],x4=xr[4],x5=xr[5];
  const float sq = x0*x0+x1*x1+x2*x2+x3*x3+x4*x4+x5*x5;
  PA[n] = make_float4(x0,x1,x2,x3);
  PB[n] = make_float4(x4,x5,sq,0.f);
}

// ---------------- kNN v4: all 64 keys/lane in registers, ONE global pivot,
//                  ONE compact pass, ONE exact u64 bitonic merge ----------------
__global__ __launch_bounds__(256) void knn_k(const float4* __restrict__ PA, const float4* __restrict__ PB,
                                             int* __restrict__ nbr){
  __shared__ float4 A4[TS];
  __shared__ float4 B4[TS];
  __shared__ unsigned skey[4][KCAP];
  __shared__ unsigned sslot[4][KCAP];
  const int t = threadIdx.x, w = t >> 6, lane = t & 63;
  const int n = blockIdx.x*4 + w;
  const int base = n & ~(NPB-1);
  const float4 qa = PA[n];
  const float4 qb = PB[n];
  const float sqn = qb.z;
  const int selfslot = n - base;

  unsigned keys[64];
  unsigned lmk = 0xFFFFFFFFu;
#pragma unroll
  for (int tile=0; tile<NPB/TS; ++tile){
    __syncthreads();   // all waves done reading previous tile
    for (int i=t; i<TS; i+=256){
      A4[i] = PA[base+tile*TS+i];
      B4[i] = PB[base+tile*TS+i];
    }
    __syncthreads();
#pragma unroll
    for (int it=0; it<16; ++it){
      const int s = it*64 + lane;
      const float4 a = A4[s];
      const float4 b = B4[s];
      const float dot = qa.x*a.x + qa.y*a.y + qa.z*a.z + qa.w*a.w + qb.x*b.x + qb.y*b.y;
      const float d2 = sqn + b.z - 2.0f*dot;
      unsigned u = __float_as_uint(d2);
      u = (u & 0x80000000u) ? ~u : (u | 0x80000000u);   // monotone float->uint
      if (tile*TS + s == selfslot) u = 0xFFFFFFFFu;     // exclude self
      keys[tile*16+it] = u;
      lmk = u < lmk ? u : lmk;
    }
  }

  // global pivot: 16th smallest of the 64 lane minima (upper bound on true 16th key)
  unsigned T = bsort32(lmk, lane);
  T = __shfl(T, 15);

  // single compact pass over register keys
  int cnt = 0;
#pragma unroll
  for (int q=0; q<64; ++q){
    const bool p = keys[q] <= T;
    const unsigned long long bb = __ballot(p);
    if (p){
      const int pos = cnt + (int)__popcll(bb & ((1ull << lane) - 1ull));
      if (pos < KCAP){
        skey[w][pos]  = keys[q];
        sslot[w][pos] = (unsigned)((q>>4)*TS + (q&15)*64 + lane);
      }
    }
    cnt += (int)__popcll(bb);
  }
  if (cnt > KCAP) cnt = KCAP;

  // final: exact top-16 over survivors (u64 = key||slot, ascending, slot tie-break)
  unsigned long long vbest;
  {
    unsigned long long v = ~0ull;
    if (lane < cnt) v = ((unsigned long long)skey[w][lane] << 32) | sslot[w][lane];
    vbest = bsort64(v, lane);
  }
  for (int c=1; c*64 < cnt; ++c){   // cold path (cnt>64 ~ never)
    const int i = c*64 + lane;
    unsigned long long v = ~0ull;
    if (i < cnt) v = ((unsigned long long)skey[w][i] << 32) | sslot[w][i];
    v = bsort64(v, lane);
    const unsigned long long r = __shfl(v, 63-lane);
    vbest = vbest < r ? vbest : r;     // bitonic sequence of the 64 smallest
#pragma unroll
    for (int j=32;j>0;j>>=1){          // cleanup merge, ascending
      const unsigned long long o = __shfl_xor(vbest, j);
      const bool keepMin = (lane & j) == 0;
      const unsigned long long mn = vbest < o ? vbest : o;
      const unsigned long long mx = vbest < o ? o : vbest;
      vbest = keepMin ? mn : mx;
    }
  }
  if (lane < 16) nbr[n*16 + lane] = base + (int)(vbest & 0xFFFFFFFFull);
}

// ---------------- layer-1 GEMM: x[NN,6] @ W1[6,256] ----------------
__global__ __launch_bounds__(256) void gemm_in6(const float* __restrict__ x, const float* __restrict__ W,
                                                float* __restrict__ h){
  const int t = blockIdx.x*256 + threadIdx.x;  // over NN*64
  const int n = t >> 6, cg = t & 63;
  const float* xr = x + n*6;
  float xv[6];
#pragma unroll
  for (int d=0; d<6; d++) xv[d] = xr[d];
  float4 acc = make_float4(0.f,0.f,0.f,0.f);
#pragma unroll
  for (int d=0; d<6; d++){
    const float4 wv = *(const float4*)(W + d*256 + cg*4);
    acc.x += xv[d]*wv.x; acc.y += xv[d]*wv.y; acc.z += xv[d]*wv.z; acc.w += xv[d]*wv.w;
  }
  *(float4*)(h + n*256 + cg*4) = acc;
}

// ---------------- residual: y[NN,128] += x@res_W + res_b ----------------
__global__ __launch_bounds__(256) void res_k(const float* __restrict__ x, const float* __restrict__ W,
                                             const float* __restrict__ b, float* __restrict__ y){
  const int t = blockIdx.x*256 + threadIdx.x;  // over NN*128
  const int n = t >> 7, c = t & 127;
  const float* xr = x + n*6;
  float acc = b[c];
#pragma unroll
  for (int d=0; d<6; d++) acc += xr[d]*W[d*128 + c];
  y[t] += acc;
}

// ---------------- attention logits: als/ald [NN,HEADS] ----------------
template<int HEADS, int C>
__global__ __launch_bounds__(256) void al_k(const float* __restrict__ h, const float* __restrict__ asrc,
                                            const float* __restrict__ adst, float* __restrict__ als,
                                            float* __restrict__ ald){
  const int t = blockIdx.x*256 + threadIdx.x;  // over NN*HEADS
  const int n = t / HEADS, hd = t % HEADS;
  const float* hp = h + (n*HEADS + hd)*C;
  const float* ap = asrc + hd*C;
  const float* dp = adst + hd*C;
  float s=0.f, d=0.f;
#pragma unroll 4
  for (int c=0;c<C;c+=4){
    const float4 v = *(const float4*)(hp+c);
    const float4 a = *(const float4*)(ap+c);
    const float4 b = *(const float4*)(dp+c);
    s += v.x*a.x + v.y*a.y + v.z*a.z + v.w*a.w;
    d += v.x*b.x + v.y*b.y + v.z*b.z + v.w*b.w;
  }
  als[t] = s; ald[t] = d;
}

// ---------------- GAT aggregation: one wave per node, 17-way softmax gather ----------------
template<int HEADS, int C>
__global__ __launch_bounds__(256) void agg_k(const float* __restrict__ h, const float* __restrict__ als,
                                             const float* __restrict__ ald, const int* __restrict__ nbr,
                                             const float* __restrict__ bias, float* __restrict__ out){
  constexpr int CT = HEADS*C;
  constexpr int F  = CT/64;
  const int w = threadIdx.x >> 6, lane = threadIdx.x & 63;
  const int n = blockIdx.x*4 + w;
  const int head = (lane*F)/C;
  const int col  = lane*F;
  const int nb = nbr[n*16 + (lane & 15)];
  const float aldn = ald[n*HEADS + head];
  float e[17];
#pragma unroll
  for (int j=0;j<17;j++){
    const int sj = (j<16) ? __shfl(nb, j) : n;
    const float v = als[sj*HEADS + head] + aldn;
    e[j] = v > 0.f ? v : 0.2f*v;
  }
  float mx = e[0];
#pragma unroll
  for (int j=1;j<17;j++) mx = fmaxf(mx, e[j]);
  float den = 0.f;
#pragma unroll
  for (int j=0;j<17;j++){ e[j] = expf(e[j]-mx); den += e[j]; }
  float acc[F];
#pragma unroll
  for (int f=0;f<F;f++) acc[f]=0.f;
#pragma unroll
  for (int j=0;j<17;j++){
    const int sj = (j<16) ? __shfl(nb, j) : n;
    const float* hp = h + sj*CT + col;
    if constexpr (F==4){
      const float4 v = *(const float4*)hp;
      acc[0] += e[j]*v.x; acc[1] += e[j]*v.y; acc[2] += e[j]*v.z; acc[3] += e[j]*v.w;
    } else {
      const float2 v = *(const float2*)hp;
      acc[0] += e[j]*v.x; acc[1] += e[j]*v.y;
    }
  }
  const float inv = 1.f/den;
  if constexpr (F==4){
    float4 o;
    o.x = gelu_f(acc[0]*inv + bias[col+0]);
    o.y = gelu_f(acc[1]*inv + bias[col+1]);
    o.z = gelu_f(acc[2]*inv + bias[col+2]);
    o.w = gelu_f(acc[3]*inv + bias[col+3]);
    *(float4*)(out + n*CT + col) = o;
  } else {
    float2 o;
    o.x = gelu_f(acc[0]*inv + bias[col+0]);
    o.y = gelu_f(acc[1]*inv + bias[col+1]);
    *(float2*)(out + n*CT + col) = o;
  }
}

// ---------------- generic fp32 tiled GEMM: [M,KC] @ [KC,NC], BM=128 BN=64 BK=32 ----------------
template<int KC, int NC, bool BIAS, bool GELU>
__global__ __launch_bounds__(256) void gemm_k(const float* __restrict__ A, const float* __restrict__ B,
                                              const float* __restrict__ bias, float* __restrict__ C){
  __shared__ float Ast[32][132];   // A chunk transposed: Ast[k][row]
  __shared__ float Bs[32][64];
  const int t  = threadIdx.x;
  const int r0 = blockIdx.x*128;
  const int c0 = blockIdx.y*64;
  const int ty = t >> 4, tx = t & 15;
  const int ar = t >> 1, ac = (t & 1)*16;
  const int br = t >> 3, bc = (t & 7)*8;
  float acc[8][4];
#pragma unroll
  for (int i=0;i<8;i++)
#pragma unroll
    for (int j=0;j<4;j++) acc[i][j] = 0.f;

#pragma unroll 1
  for (int kc=0; kc<KC; kc+=32){
    const float* Ap = A + (size_t)(r0+ar)*KC + kc + ac;
    float4 av[4];
#pragma unroll
    for (int u=0;u<4;u++) av[u] = *(const float4*)(Ap + u*4);
#pragma unroll
    for (int u=0;u<4;u++){
      Ast[ac+u*4+0][ar] = av[u].x;
      Ast[ac+u*4+1][ar] = av[u].y;
      Ast[ac+u*4+2][ar] = av[u].z;
      Ast[ac+u*4+3][ar] = av[u].w;
    }
    const float* Bp = B + (size_t)(kc+br)*NC + c0 + bc;
    *(float4*)&Bs[br][bc]   = *(const float4*)Bp;
    *(float4*)&Bs[br][bc+4] = *(const float4*)(Bp+4);
    __syncthreads();
#pragma unroll
    for (int k=0;k<32;k++){
      const float4 a0 = *(const float4*)&Ast[k][ty*8];
      const float4 a1 = *(const float4*)&Ast[k][ty*8+4];
      const float4 bv = *(const float4*)&Bs[k][tx*4];
      const float avr[8] = {a0.x,a0.y,a0.z,a0.w,a1.x,a1.y,a1.z,a1.w};
      const float bbr[4] = {bv.x,bv.y,bv.z,bv.w};
#pragma unroll
      for (int i=0;i<8;i++)
#pragma unroll
        for (int j=0;j<4;j++)
          acc[i][j] += avr[i]*bbr[j];
    }
    __syncthreads();
  }
#pragma unroll
  for (int i=0;i<8;i++){
    const int r = r0 + ty*8 + i;
    float vv[4];
#pragma unroll
    for (int j=0;j<4;j++){
      float v = acc[i][j];
      if constexpr (BIAS) v += bias[c0 + tx*4 + j];
      if constexpr (GELU) v = gelu_f(v);
      vv[j] = v;
    }
    *(float4*)(C + (size_t)r*NC + c0 + tx*4) = make_float4(vv[0],vv[1],vv[2],vv[3]);
  }
}

// ---------------- final tiny GEMM: [NN,64] @ [64,6] + b ----------------
__global__ __launch_bounds__(256) void m3_k(const float* __restrict__ A, const float* __restrict__ W,
                                            const float* __restrict__ bias, float* __restrict__ out){
  __shared__ float Wl[64*6];
  __shared__ float bl[6];
  const int t = threadIdx.x;
  for (int i=t; i<384; i+=256) Wl[i] = W[i];
  if (t < 6) bl[t] = bias[t];
  __syncthreads();
  const int n = blockIdx.x*256 + t;
  const float* ap = A + n*64;
  float acc[6] = {0.f,0.f,0.f,0.f,0.f,0.f};
  for (int k=0;k<64;k+=4){
    const float4 v = *(const float4*)(ap+k);
    const float vr[4] = {v.x,v.y,v.z,v.w};
#pragma unroll
    for (int u=0;u<4;u++)
#pragma unroll
      for (int j=0;j<6;j++)
        acc[j] += vr[u]*Wl[(k+u)*6+j];
  }
#pragma unroll
  for (int j=0;j<6;j++) out[n*6+j] = acc[j] + bl[j];
}

extern "C" void kernel_launch(void* const* d_in, const int* in_sizes, int n_in,
                              void* d_out, int out_size, void* d_ws, size_t ws_size,
                              hipStream_t stream){
  (void)in_sizes; (void)n_in; (void)out_size; (void)ws_size;
  const float* x      = (const float*)d_in[0];
  const float* W1     = (const float*)d_in[1];
  const float* a_src1 = (const float*)d_in[2];
  const float* a_dst1 = (const float*)d_in[3];
  const float* b1     = (const float*)d_in[4];
  const float* W2     = (const float*)d_in[5];
  const float* a_src2 = (const float*)d_in[6];
  const float* a_dst2 = (const float*)d_in[7];
  const float* b2     = (const float*)d_in[8];
  const float* W3     = (const float*)d_in[9];
  const float* a_src3 = (const float*)d_in[10];
  const float* a_dst3 = (const float*)d_in[11];
  const float* b3     = (const float*)d_in[12];
  const float* res_W  = (const float*)d_in[13];
  const float* res_b  = (const float*)d_in[14];
  const float* m1_W   = (const float*)d_in[15];
  const float* m1_b   = (const float*)d_in[16];
  const float* m2_W   = (const float*)d_in[17];
  const float* m2_b   = (const float*)d_in[18];
  const float* m3_W   = (const float*)d_in[19];
  const float* m3_b   = (const float*)d_in[20];
  float* out = (float*)d_out;

  char* wsb = (char*)d_ws;
  int*   nbr = (int*)wsb;                                   // 1 MB
  float* H   = (float*)(wsb + (1u<<20));                    // 16 MB
  float* Y   = (float*)(wsb + (1u<<20) + (16u<<20));        // 16 MB
  float* ALS = (float*)(wsb + (1u<<20) + (32u<<20));        // 256 KB
  float* ALD = ALS + NN*4;                                  // 256 KB
  float4* PA = (float4*)(wsb + (1u<<20) + (32u<<20) + (512u<<10)); // 256 KB
  float4* PB = PA + NN;                                            // 256 KB

  pack_k<<<NN/256, 256, 0, stream>>>(x, PA, PB);
  knn_k<<<NN/4, 256, 0, stream>>>(PA, PB, nbr);

  // GAT layer 1: 6 -> 4x64
  gemm_in6<<<NN*64/256, 256, 0, stream>>>(x, W1, H);
  al_k<4,64><<<NN*4/256, 256, 0, stream>>>(H, a_src1, a_dst1, ALS, ALD);
  agg_k<4,64><<<NN/4, 256, 0, stream>>>(H, ALS, ALD, nbr, b1, Y);

  // GAT layer 2: 256 -> 4x64
  gemm_k<256,256,false,false><<<dim3(NN/128, 4), 256, 0, stream>>>(Y, W2, nullptr, H);
  al_k<4,64><<<NN*4/256, 256, 0, stream>>>(H, a_src2, a_dst2, ALS, ALD);
  agg_k<4,64><<<NN/4, 256, 0, stream>>>(H, ALS, ALD, nbr, b2, Y);

  // GAT layer 3: 256 -> 1x128
  gemm_k<256,128,false,false><<<dim3(NN/128, 2), 256, 0, stream>>>(Y, W3, nullptr, H);
  al_k<1,128><<<NN/256, 256, 0, stream>>>(H, a_src3, a_dst3, ALS, ALD);
  agg_k<1,128><<<NN/4, 256, 0, stream>>>(H, ALS, ALD, nbr, b3, Y);

  // residual + MLP
  res_k<<<NN*128/256, 256, 0, stream>>>(x, res_W, res_b, Y);
  gemm_k<128,128,true,true><<<dim3(NN/128, 2), 256, 0, stream>>>(Y, m1_W, m1_b, H);
  gemm_k<128,64,true,true><<<dim3(NN/128, 1), 256, 0, stream>>>(H, m2_W, m2_b, Y);
  m3_k<<<NN/256, 256, 0, stream>>>(Y, m3_W, m3_b, out);
}